// Round 2
// baseline (1495.118 us; speedup 1.0000x reference)
//
#include <hip/hip_runtime.h>
#include <cstdint>
#include <cstddef>

// Problem constants (match reference setup_inputs)
#define Bb   256
#define Tt   250
#define DIN  700
#define Hh   128
#define DOUT 20

// ---------------------------------------------------------------------------
// Phase 1: H1[b*T+t][h] = x[b][t][:] @ W1[:,h] + b1[h]
// M=64000, K=700, N=128. 128x128 tile, BK=20, 256 threads, 8x8 micro-tile.
// NEW this round (T14 reg-staged pipeline): next tile's global loads are
// issued into registers BEFORE the current tile's compute, committed to LDS
// after the post-compute barrier. Global latency (~500-900cy) hides under
// the 20x64-FMA block instead of sitting serially between barriers.
// ---------------------------------------------------------------------------
constexpr int BM  = 128;
constexpr int BK  = 20;
constexpr int BN  = 128;
constexpr int BMP = BM + 4;   // padded row length for Ast (staging writes)

__device__ __forceinline__ int bswz(int g) { return g ^ (g >> 3); }

__global__ __launch_bounds__(256, 2) void gemm_h1(const float* __restrict__ x,
                                                  const float* __restrict__ W1,
                                                  const float* __restrict__ b1,
                                                  float* __restrict__ H1) {
    __shared__ float Ast[BK][BMP];  // x tile, TRANSPOSED: Ast[k][m], padded
    __shared__ float Bs[BK][BN];    // W1 tile, column-group swizzled

    const int tid = threadIdx.x;
    const int tx  = tid & 15;       // col group: cols tx*8 .. +7
    const int ty  = tid >> 4;       // row group: rows ty*8 .. +7
    const int m0  = blockIdx.x * BM;

    const int c0 = bswz(tx * 2) * 4;
    const int c1 = bswz(tx * 2 + 1) * 4;

    // Fixed staging slots: idx = tid + 256*j (j=0,1 always; j=2 iff tid<128),
    // covering idx 0..639 (= 128 rows x 5 float4 for A; 20 rows x 32 float4 for B).
    const int arow0 = tid / 5,         akq0 = (tid - arow0 * 5) * 4;
    const int ai1   = tid + 256;
    const int arow1 = ai1 / 5,         akq1 = (ai1 - arow1 * 5) * 4;
    const int ai2   = tid + 512;
    const int arow2 = ai2 / 5,         akq2 = (ai2 - arow2 * 5) * 4; // tid<128 only
    const int bkr0  = tid >> 5,        bg   = tid & 31;              // bkr1=+8, bkr2=+16
    const int bcs   = bswz(bg) * 4;    // swizzled column start for Bs stores
    const bool has2 = (tid < 128);

    float4 va0, va1, va2, vb0, vb1, vb2;

#define LOAD_TILE(K0)                                                         \
    {                                                                         \
        const int k0_ = (K0);                                                 \
        va0 = *(const float4*)&x[(size_t)(m0 + arow0) * DIN + (k0_ + akq0)];  \
        va1 = *(const float4*)&x[(size_t)(m0 + arow1) * DIN + (k0_ + akq1)];  \
        if (has2)                                                             \
            va2 = *(const float4*)&x[(size_t)(m0 + arow2) * DIN + (k0_ + akq2)]; \
        vb0 = *(const float4*)&W1[(size_t)(k0_ + bkr0) * BN + bg * 4];        \
        vb1 = *(const float4*)&W1[(size_t)(k0_ + bkr0 + 8) * BN + bg * 4];    \
        if (has2)                                                             \
            vb2 = *(const float4*)&W1[(size_t)(k0_ + bkr0 + 16) * BN + bg * 4]; \
    }

#define STORE_TILE()                                                          \
    {                                                                         \
        Ast[akq0 + 0][arow0] = va0.x; Ast[akq0 + 1][arow0] = va0.y;           \
        Ast[akq0 + 2][arow0] = va0.z; Ast[akq0 + 3][arow0] = va0.w;           \
        Ast[akq1 + 0][arow1] = va1.x; Ast[akq1 + 1][arow1] = va1.y;           \
        Ast[akq1 + 2][arow1] = va1.z; Ast[akq1 + 3][arow1] = va1.w;           \
        if (has2) {                                                           \
            Ast[akq2 + 0][arow2] = va2.x; Ast[akq2 + 1][arow2] = va2.y;       \
            Ast[akq2 + 2][arow2] = va2.z; Ast[akq2 + 3][arow2] = va2.w;       \
        }                                                                     \
        *(float4*)&Bs[bkr0][bcs]      = vb0;                                  \
        *(float4*)&Bs[bkr0 + 8][bcs]  = vb1;                                  \
        if (has2) *(float4*)&Bs[bkr0 + 16][bcs] = vb2;                        \
    }

    float acc[8][8];
#pragma unroll
    for (int r = 0; r < 8; ++r)
#pragma unroll
        for (int c = 0; c < 8; ++c) acc[r][c] = 0.f;

    // prologue: stage tile 0
    LOAD_TILE(0);
    STORE_TILE();
    __syncthreads();

    for (int k0 = 0; k0 < DIN; k0 += BK) {
        const bool more = (k0 + BK < DIN);
        if (more) LOAD_TILE(k0 + BK);   // in flight under the compute below

#pragma unroll
        for (int kk = 0; kk < BK; ++kk) {
            float a[8], bv[8];
            *(float4*)&a[0]  = *(const float4*)&Ast[kk][ty * 8];
            *(float4*)&a[4]  = *(const float4*)&Ast[kk][ty * 8 + 4];
            *(float4*)&bv[0] = *(const float4*)&Bs[kk][c0];
            *(float4*)&bv[4] = *(const float4*)&Bs[kk][c1];
#pragma unroll
            for (int r = 0; r < 8; ++r)
#pragma unroll
                for (int c = 0; c < 8; ++c)
                    acc[r][c] = fmaf(a[r], bv[c], acc[r][c]);
        }
        __syncthreads();                // everyone done reading LDS
        if (more) STORE_TILE();         // commit staged regs
        __syncthreads();                // stores visible before next compute
    }
#undef LOAD_TILE
#undef STORE_TILE

    float bb[8];
#pragma unroll
    for (int c = 0; c < 8; ++c) bb[c] = b1[tx * 8 + c];

#pragma unroll
    for (int r = 0; r < 8; ++r) {
        size_t row = (size_t)(m0 + ty * 8 + r);
        float4 o0, o1;
        o0.x = acc[r][0] + bb[0]; o0.y = acc[r][1] + bb[1];
        o0.z = acc[r][2] + bb[2]; o0.w = acc[r][3] + bb[3];
        o1.x = acc[r][4] + bb[4]; o1.y = acc[r][5] + bb[5];
        o1.z = acc[r][6] + bb[6]; o1.w = acc[r][7] + bb[7];
        *(float4*)&H1[row * Hh + tx * 8]     = o0;
        *(float4*)&H1[row * Hh + tx * 8 + 4] = o1;
    }
}

// ---------------------------------------------------------------------------
// Phase 2: recurrence. H1 delivered through a 64 KB LDS ring (128 steps x
// 512 B) filled by async global_load_lds (width 16), 4 chunks of 32 steps,
// counted-vmcnt waits ONLY at 32-step chunk boundaries.
//  - issue->wait distance = 2 chunks (~64 step bodies) >> HBM latency (~900cy)
//  - per-step consume is from LDS via the 4-slot register pipeline
//  - spike-gather vmcnt drains are near-free (chunk loads retire early)
// Arithmetic and its ordering are bit-identical to the R0 passing kernel.
// (Unchanged from the R1 submission — failure was container-level, theory
//  untested; addresses re-audited in bounds, waits cannot deadlock.)
// ---------------------------------------------------------------------------

#define WAITV(N)                                                       \
    asm volatile("s_waitcnt vmcnt(" #N ")" ::: "memory");              \
    __builtin_amdgcn_sched_barrier(0)

// Chunk c covers steps [32c, min(32c+32,250)). 1 instr = 1 KB = 2 steps.
// Ring slot for step t: byte (t & 127) * 512; chunk c region: (c&3)*16384.
__device__ __forceinline__ void issue_chunk(const float* __restrict__ h1p,
                                            float* ring, int c, int n,
                                            int lane) {
    const char* g = (const char*)h1p + (size_t)c * 16384 + (size_t)lane * 16;
    char* l = (char*)ring + ((c & 3) * 16384);
    for (int i = 0; i < n; ++i) {
        __builtin_amdgcn_global_load_lds(
            (const __attribute__((address_space(1))) uint32_t*)(g + (size_t)i * 1024),
            (__attribute__((address_space(3))) uint32_t*)(l + i * 1024),
            16, 0, 0);
    }
}

__global__ __launch_bounds__(64) void recurrent(
    const float* __restrict__ H1,   const float* __restrict__ rcW1,
    const float* __restrict__ rcb1, const float* __restrict__ W2,
    const float* __restrict__ b2,   const float* __restrict__ rcW2,
    const float* __restrict__ rcb2, const float* __restrict__ W3,
    const float* __restrict__ b3,   float* __restrict__ out) {

    __shared__ float ring[128 * Hh];   // 64 KB: 128 steps x 128 floats

    const int lane = threadIdx.x;     // 0..63
    const int b    = blockIdx.x;

    const float rcb1x = rcb1[lane], rcb1y = rcb1[lane + 64];
    const float bb2x  = b2[lane]      + rcb2[lane];
    const float bb2y  = b2[lane + 64] + rcb2[lane + 64];
    const float* __restrict__ h1p = H1 + (size_t)b * Tt * Hh;

    float v1x = 0.f, v1y = 0.f, v2x = 0.f, v2y = 0.f;
    float cntx = 0.f, cnty = 0.f;
    float u1gx = 0.f, u1gy = 0.f;     // rcW1 gather result (prev step)
    float u2gx = 0.f, u2gy = 0.f;     // rcW2 gather result (prev step)

    // prologue: fill ring chunks 0..2 (steps 0..95), wait chunk 0
    issue_chunk(h1p, ring, 0, 16, lane);
    issue_chunk(h1p, ring, 1, 16, lane);
    issue_chunk(h1p, ring, 2, 16, lane);
    WAITV(32);

    // 4-deep register pipeline (slot j holds step t with t%4==j), from LDS
    float h1xs[4], h1ys[4];
#pragma unroll
    for (int j = 0; j < 4; ++j) {
        h1xs[j] = ring[(j << 7) + lane];
        h1ys[j] = ring[(j << 7) + lane + 64];
    }

#define STEP(T, J)                                                            \
    {                                                                         \
        const int t_ = (T);                                                   \
        /* ---- LIF 1 (consume slot J, then refill it for t+4 from LDS) */    \
        const float u1xv = h1xs[J] + rcb1x + u1gx;                            \
        const float u1yv = h1ys[J] + rcb1y + u1gy;                            \
        int tp = t_ + 4; tp = (tp < Tt) ? tp : (Tt - 1);                      \
        const float* rp_ = &ring[(tp & 127) << 7];                            \
        h1xs[J] = rp_[lane];                                                  \
        h1ys[J] = rp_[lane + 64];                                             \
        v1x = v1x + (u1xv - v1x) * 0.5f;                                      \
        v1y = v1y + (u1yv - v1y) * 0.5f;                                      \
        const bool s1x = (v1x >= 1.0f);                                       \
        const bool s1y = (v1y >= 1.0f);                                       \
        if (s1x) v1x = 0.f;                                                   \
        if (s1y) v1y = 0.f;                                                   \
        const unsigned long long a0 = __ballot((int)s1x);                     \
        const unsigned long long a1 = __ballot((int)s1y);                     \
        /* ---- layer-1 spike fanout: W2 (this step) + rcW1 (next) ---- */    \
        float uW2x = 0.f, uW2y = 0.f, g1x = 0.f, g1y = 0.f;                   \
        if (a0 | a1) {                                                        \
            unsigned long long m = a0;                                        \
            int base = 0;                                                     \
            for (int hlf = 0; hlf < 2; ++hlf) {                               \
                while (m) {                                                   \
                    const int k = (int)__ffsll(m) - 1 + base;                 \
                    m &= (m - 1ull);                                          \
                    const float* __restrict__ pw = W2 + k * Hh;               \
                    const float* __restrict__ pr = rcW1 + k * Hh;             \
                    uW2x += pw[lane]; uW2y += pw[lane + 64];                  \
                    g1x  += pr[lane]; g1y  += pr[lane + 64];                  \
                }                                                             \
                m = a1; base = 64;                                            \
            }                                                                 \
        }                                                                     \
        u1gx = g1x; u1gy = g1y;                                               \
        /* ---- LIF 2 ---- */                                                 \
        const float u2xv = bb2x + uW2x + u2gx;                                \
        const float u2yv = bb2y + uW2y + u2gy;                                \
        v2x = v2x + (u2xv - v2x) * 0.5f;                                      \
        v2y = v2y + (u2yv - v2y) * 0.5f;                                      \
        const bool s2x = (v2x >= 1.0f);                                       \
        const bool s2y = (v2y >= 1.0f);                                       \
        if (s2x) v2x = 0.f;                                                   \
        if (s2y) v2y = 0.f;                                                   \
        cntx += s2x ? 1.f : 0.f;                                              \
        cnty += s2y ? 1.f : 0.f;                                              \
        const unsigned long long c0m = __ballot((int)s2x);                    \
        const unsigned long long c1m = __ballot((int)s2y);                    \
        float g2x = 0.f, g2y = 0.f;                                           \
        if (c0m | c1m) {                                                      \
            unsigned long long m = c0m;                                       \
            int base = 0;                                                     \
            for (int hlf = 0; hlf < 2; ++hlf) {                               \
                while (m) {                                                   \
                    const int k = (int)__ffsll(m) - 1 + base;                 \
                    m &= (m - 1ull);                                          \
                    const float* __restrict__ pr = rcW2 + k * Hh;             \
                    g2x += pr[lane]; g2y += pr[lane + 64];                    \
                }                                                             \
                m = c1m; base = 64;                                           \
            }                                                                 \
        }                                                                     \
        u2gx = g2x; u2gy = g2y;                                               \
    }

    // chunk-paced main loop: 8 chunks; c=0..6 full (32 steps), c=7 tail.
    // vmcnt discipline (in-order retirement):
    //   c<=4: issue chunk c+3 (16 instr; chunk 7 = 13), then vmcnt(16)
    //         (only just-issued chunk may remain outstanding => c+2 done)
    //   c==5: vmcnt(13) (only chunk 7 may remain => chunk 6 done)
    //   c>=6: vmcnt(0)  (chunk 7 done; issued 2 boundaries ago, no stall)
#pragma unroll 1
    for (int c = 0; c < 8; ++c) {
        if (c <= 4) issue_chunk(h1p, ring, c + 3, (c == 4) ? 13 : 16, lane);
        if (c < 5)       { WAITV(16); }
        else if (c == 5) { WAITV(13); }
        else             { WAITV(0);  }
        const int ng = (c < 7) ? 8 : 6;
        const int t0 = c << 5;
#pragma unroll 1
        for (int g = 0; g < ng; ++g) {
            const int t = t0 + (g << 2);
            STEP(t + 0, 0)
            STEP(t + 1, 1)
            STEP(t + 2, 2)
            STEP(t + 3, 3)
        }
    }
    STEP(248, 0)
    STEP(249, 1)
#undef STEP

    // ---- readout: out[b] = cnt2 @ W3 + T*b3 (ring reused as scratch) ----
    ring[lane]      = cntx;
    ring[lane + 64] = cnty;
    __syncthreads();
    if (lane < DOUT) {
        float o = (float)Tt * b3[lane];
#pragma unroll 8
        for (int k = 0; k < Hh; ++k) o += ring[k] * W3[k * DOUT + lane];
        out[b * DOUT + lane] = o;
    }
}

// ---------------------------------------------------------------------------
extern "C" void kernel_launch(void* const* d_in, const int* in_sizes, int n_in,
                              void* d_out, int out_size, void* d_ws, size_t ws_size,
                              hipStream_t stream) {
    const float* x    = (const float*)d_in[0];
    const float* W1   = (const float*)d_in[1];
    const float* b1   = (const float*)d_in[2];
    const float* rcW1 = (const float*)d_in[3];
    const float* rcb1 = (const float*)d_in[4];
    const float* W2   = (const float*)d_in[5];
    const float* b2   = (const float*)d_in[6];
    const float* rcW2 = (const float*)d_in[7];
    const float* rcb2 = (const float*)d_in[8];
    const float* W3   = (const float*)d_in[9];
    const float* b3   = (const float*)d_in[10];

    float* out = (float*)d_out;
    float* H1  = (float*)d_ws;   // 64000 x 128 f32 = 32.77 MB

    gemm_h1<<<(Bb * Tt) / BM, 256, 0, stream>>>(x, W1, b1, H1);
    recurrent<<<Bb, 64, 0, stream>>>(H1, rcW1, rcb1, W2, b2, rcW2, rcb2, W3,
                                     b3, out);
}

// Round 3
// 460.830 us; speedup vs baseline: 3.2444x; 3.2444x over previous
//
#include <hip/hip_runtime.h>
#include <cstdint>
#include <cstddef>

// Problem constants (match reference setup_inputs)
#define Bb   256
#define Tt   250
#define DIN  700
#define Hh   128
#define DOUT 20

// ---------------------------------------------------------------------------
// Phase 1: H1[b*T+t][h] = x[b][t][:] @ W1[:,h] + b1[h]
// M=64000, K=700, N=128. 128x128 tile, BK=20, 256 threads, 8x8 micro-tile.
// EXACT R0 version (220 us, VGPR 92). R2's reg-staging spilled (VGPR capped
// at 128 -> scratch: WRITE_SIZE 32MB->3.2GB). Reverted; do not touch.
// ---------------------------------------------------------------------------
constexpr int BM  = 128;
constexpr int BK  = 20;
constexpr int BN  = 128;
constexpr int BMP = BM + 4;   // padded row length for Ast (staging writes)

__device__ __forceinline__ int bswz(int g) { return g ^ (g >> 3); }

__global__ __launch_bounds__(256, 2) void gemm_h1(const float* __restrict__ x,
                                                  const float* __restrict__ W1,
                                                  const float* __restrict__ b1,
                                                  float* __restrict__ H1) {
    __shared__ float Ast[BK][BMP];  // x tile, TRANSPOSED: Ast[k][m], padded
    __shared__ float Bs[BK][BN];    // W1 tile, column-group swizzled

    const int tid = threadIdx.x;
    const int tx  = tid & 15;       // col group: cols tx*8 .. +7
    const int ty  = tid >> 4;       // row group: rows ty*8 .. +7
    const int m0  = blockIdx.x * BM;

    const int c0 = bswz(tx * 2) * 4;
    const int c1 = bswz(tx * 2 + 1) * 4;

    float acc[8][8];
#pragma unroll
    for (int r = 0; r < 8; ++r)
#pragma unroll
        for (int c = 0; c < 8; ++c) acc[r][c] = 0.f;

    for (int k0 = 0; k0 < DIN; k0 += BK) {
#pragma unroll
        for (int idx = tid; idx < 640; idx += 256) {
            int row = idx / 5;
            int kq  = (idx - row * 5) * 4;
            const float4 v =
                *(const float4*)&x[(size_t)(m0 + row) * DIN + (k0 + kq)];
            Ast[kq + 0][row] = v.x;
            Ast[kq + 1][row] = v.y;
            Ast[kq + 2][row] = v.z;
            Ast[kq + 3][row] = v.w;
        }
#pragma unroll
        for (int idx = tid; idx < 640; idx += 256) {
            int kr = idx >> 5;
            int g  = idx & 31;
            *(float4*)&Bs[kr][bswz(g) * 4] =
                *(const float4*)&W1[(size_t)(k0 + kr) * BN + g * 4];
        }
        __syncthreads();

#pragma unroll
        for (int kk = 0; kk < BK; ++kk) {
            float a[8], bv[8];
            *(float4*)&a[0]  = *(const float4*)&Ast[kk][ty * 8];
            *(float4*)&a[4]  = *(const float4*)&Ast[kk][ty * 8 + 4];
            *(float4*)&bv[0] = *(const float4*)&Bs[kk][c0];
            *(float4*)&bv[4] = *(const float4*)&Bs[kk][c1];
#pragma unroll
            for (int r = 0; r < 8; ++r)
#pragma unroll
                for (int c = 0; c < 8; ++c)
                    acc[r][c] = fmaf(a[r], bv[c], acc[r][c]);
        }
        __syncthreads();
    }

    float bb[8];
#pragma unroll
    for (int c = 0; c < 8; ++c) bb[c] = b1[tx * 8 + c];

#pragma unroll
    for (int r = 0; r < 8; ++r) {
        size_t row = (size_t)(m0 + ty * 8 + r);
        float4 o0, o1;
        o0.x = acc[r][0] + bb[0]; o0.y = acc[r][1] + bb[1];
        o0.z = acc[r][2] + bb[2]; o0.w = acc[r][3] + bb[3];
        o1.x = acc[r][4] + bb[4]; o1.y = acc[r][5] + bb[5];
        o1.z = acc[r][6] + bb[6]; o1.w = acc[r][7] + bb[7];
        *(float4*)&H1[row * Hh + tx * 8]     = o0;
        *(float4*)&H1[row * Hh + tx * 8 + 4] = o1;
    }
}

// ---------------------------------------------------------------------------
// Phase 2: recurrence. R2 proved h1-delivery was NOT the bottleneck (ring
// changed nothing: ~223us both ways). Remaining latency-serial term: the
// per-spike gather (ffs -> 4 loads -> waitcnt -> add, ~250cy L2 round each,
// ~8 spikes/step ~= 2140cy/step observed). This round:
//  - W2 + rcW1 staged in LDS (128 KB, async global_load_lds preload):
//    layer-1 gather latency 250 -> ~120cy. Layer-1 is same-step critical
//    (uW2 feeds LIF2 of the same step).
//  - 4-wide index-batched gather: up to 4 spikes share ONE latency round.
//  - layer-2 (rcW2, global) gather DEFERRED: loads issued end of step t into
//    named regs, applied at t+1's LIF2 (latency hides under t+1's LIF1 +
//    layer-1 gather). >3 spikes (rare): in-step ascending walk fallback.
// All accumulation trees preserved term-for-term ascending-k; only exact
// +0.0f terms added => bit-identical results (absmax 0.0).
// h1 ring shrunk to 32 steps / 16 KB (machinery proven in R2). LDS 144 KiB.
// ---------------------------------------------------------------------------

#define WAITV(N)                                                       \
    asm volatile("s_waitcnt vmcnt(" #N ")" ::: "memory");              \
    __builtin_amdgcn_sched_barrier(0)

__device__ __forceinline__ void gll16(const void* g, void* l) {
    __builtin_amdgcn_global_load_lds(
        (const __attribute__((address_space(1))) uint32_t*)g,
        (__attribute__((address_space(3))) uint32_t*)l, 16, 0, 0);
}

// Chunk c covers steps [8c, 8c+8); 4 instrs x 1024 B (chunk 31: 1 instr).
// hg already includes lane*16.
__device__ __forceinline__ void issue_chunk(const char* hg, char* ringb,
                                            int c, int n) {
    const char* g = hg + (size_t)c * 4096;
    char* l = ringb + (c & 3) * 4096;
    for (int i = 0; i < n; ++i) gll16(g + (size_t)i * 1024, l + i * 1024);
}

// Ascending-index extraction from the 128-bit (mlo,mhi) spike mask.
// EXTR: mask known non-empty. EXTR2: may be empty (K stays -1).
#define EXTR(K)                                                        \
    if (mlo) { K = (int)__ffsll(mlo) - 1; mlo &= mlo - 1ull; }         \
    else     { K = 64 + (int)__ffsll(mhi) - 1; mhi &= mhi - 1ull; }
#define EXTR2(K)                                                       \
    if (mlo)      { K = (int)__ffsll(mlo) - 1; mlo &= mlo - 1ull; }    \
    else if (mhi) { K = 64 + (int)__ffsll(mhi) - 1; mhi &= mhi - 1ull; }

__global__ __launch_bounds__(64) void recurrent(
    const float* __restrict__ H1,   const float* __restrict__ rcW1,
    const float* __restrict__ rcb1, const float* __restrict__ W2,
    const float* __restrict__ b2,   const float* __restrict__ rcW2,
    const float* __restrict__ rcb2, const float* __restrict__ W3,
    const float* __restrict__ b3,   float* __restrict__ out) {

    __shared__ float W2ls[Hh * Hh];    // 64 KB
    __shared__ float rcW1ls[Hh * Hh];  // 64 KB
    __shared__ float ring[32 * Hh];    // 16 KB: 32 steps x 128 floats

    const int lane = threadIdx.x;     // 0..63
    const int b    = blockIdx.x;

    const float rcb1x = rcb1[lane], rcb1y = rcb1[lane + 64];
    const float bb2x  = b2[lane]      + rcb2[lane];
    const float bb2y  = b2[lane + 64] + rcb2[lane + 64];
    const float* __restrict__ h1p = H1 + (size_t)b * Tt * Hh;

    // ---- async preload: W2, rcW1 -> LDS (linear copies), ring chunks 0..2
    {
        const char* g2 = (const char*)W2 + lane * 16;
        const char* g1 = (const char*)rcW1 + lane * 16;
        char* l2 = (char*)W2ls;
        char* l1 = (char*)rcW1ls;
#pragma unroll 1
        for (int i = 0; i < 64; ++i) gll16(g2 + (size_t)i * 1024, l2 + i * 1024);
#pragma unroll 1
        for (int i = 0; i < 64; ++i) gll16(g1 + (size_t)i * 1024, l1 + i * 1024);
    }
    const char* hg = (const char*)h1p + lane * 16;
    char* ringb = (char*)ring;
    issue_chunk(hg, ringb, 0, 4);
    issue_chunk(hg, ringb, 1, 4);
    issue_chunk(hg, ringb, 2, 4);
    WAITV(4);   // all but chunk 2 retired: weights + chunks 0,1 ready

    float v1x = 0.f, v1y = 0.f, v2x = 0.f, v2y = 0.f;
    float cntx = 0.f, cnty = 0.f;
    float u1gx = 0.f, u1gy = 0.f;     // rcW1 gather result (prev step)
    // deferred layer-2 gather state (loads from step t, applied at t+1)
    float l0x = 0.f, l0y = 0.f, l1x = 0.f, l1y = 0.f, l2x = 0.f, l2y = 0.f;
    bool  f0 = false, f1 = false, f2 = false;

    // 4-deep register pipeline (slot j holds step t with t%4==j), from ring
    float h1xs[4], h1ys[4];
#pragma unroll
    for (int j = 0; j < 4; ++j) {
        h1xs[j] = ring[(j << 7) + lane];
        h1ys[j] = ring[(j << 7) + lane + 64];
    }

#define STEP(T, J)                                                            \
    {                                                                         \
        const int t_ = (T);                                                   \
        /* ---- LIF 1 (consume slot J, refill it for t+4 from ring) ---- */   \
        const float u1xv = h1xs[J] + rcb1x + u1gx;                            \
        const float u1yv = h1ys[J] + rcb1y + u1gy;                            \
        int tp = t_ + 4; tp = (tp < Tt) ? tp : (Tt - 1);                      \
        const float* rp_ = &ring[(tp & 31) << 7];                             \
        h1xs[J] = rp_[lane];                                                  \
        h1ys[J] = rp_[lane + 64];                                             \
        v1x = v1x + (u1xv - v1x) * 0.5f;                                      \
        v1y = v1y + (u1yv - v1y) * 0.5f;                                      \
        const bool s1x = (v1x >= 1.0f);                                       \
        const bool s1y = (v1y >= 1.0f);                                       \
        if (s1x) v1x = 0.f;                                                   \
        if (s1y) v1y = 0.f;                                                   \
        const unsigned long long a0 = __ballot((int)s1x);                     \
        const unsigned long long a1 = __ballot((int)s1y);                     \
        /* ---- layer-1 fanout from LDS, 4-wide batched, ascending k ---- */  \
        float uW2x = 0.f, uW2y = 0.f, g1x = 0.f, g1y = 0.f;                   \
        if (a0 | a1) {                                                        \
            unsigned long long mlo = a0, mhi = a1;                            \
            while (mlo | mhi) {                                               \
                int k0; int k1 = -1; int k2 = -1; int k3 = -1;                \
                EXTR(k0) EXTR2(k1) EXTR2(k2) EXTR2(k3)                        \
                const int i0 = k0 << 7;                                       \
                const int i1 = (k1 >= 0 ? k1 : k0) << 7;                      \
                const int i2 = (k2 >= 0 ? k2 : k0) << 7;                      \
                const int i3 = (k3 >= 0 ? k3 : k0) << 7;                      \
                const float w0x = W2ls[i0 + lane],   w0y = W2ls[i0 + 64 + lane];   \
                const float r0x = rcW1ls[i0 + lane], r0y = rcW1ls[i0 + 64 + lane]; \
                const float w1x = W2ls[i1 + lane],   w1y = W2ls[i1 + 64 + lane];   \
                const float r1x = rcW1ls[i1 + lane], r1y = rcW1ls[i1 + 64 + lane]; \
                const float w2x = W2ls[i2 + lane],   w2y = W2ls[i2 + 64 + lane];   \
                const float r2x = rcW1ls[i2 + lane], r2y = rcW1ls[i2 + 64 + lane]; \
                const float w3x = W2ls[i3 + lane],   w3y = W2ls[i3 + 64 + lane];   \
                const float r3x = rcW1ls[i3 + lane], r3y = rcW1ls[i3 + 64 + lane]; \
                uW2x += w0x; uW2y += w0y; g1x += r0x; g1y += r0y;             \
                if (k1 >= 0) { uW2x += w1x; uW2y += w1y; g1x += r1x; g1y += r1y; } \
                if (k2 >= 0) { uW2x += w2x; uW2y += w2y; g1x += r2x; g1y += r2y; } \
                if (k3 >= 0) { uW2x += w3x; uW2y += w3y; g1x += r3x; g1y += r3y; } \
            }                                                                 \
        }                                                                     \
        u1gx = g1x; u1gy = g1y;                                               \
        /* ---- LIF 2 (apply deferred rcW2 gather from step t-1) ---- */      \
        const float u2gx =                                                    \
            ((f0 ? l0x : 0.f) + (f1 ? l1x : 0.f)) + (f2 ? l2x : 0.f);         \
        const float u2gy =                                                    \
            ((f0 ? l0y : 0.f) + (f1 ? l1y : 0.f)) + (f2 ? l2y : 0.f);         \
        const float u2xv = bb2x + uW2x + u2gx;                                \
        const float u2yv = bb2y + uW2y + u2gy;                                \
        v2x = v2x + (u2xv - v2x) * 0.5f;                                      \
        v2y = v2y + (u2yv - v2y) * 0.5f;                                      \
        const bool s2x = (v2x >= 1.0f);                                       \
        const bool s2y = (v2y >= 1.0f);                                       \
        if (s2x) v2x = 0.f;                                                   \
        if (s2y) v2y = 0.f;                                                   \
        cntx += s2x ? 1.f : 0.f;                                              \
        cnty += s2y ? 1.f : 0.f;                                              \
        const unsigned long long c0m = __ballot((int)s2x);                    \
        const unsigned long long c1m = __ballot((int)s2y);                    \
        /* ---- layer-2 rcW2 gather: issue now, apply next step ---- */       \
        f0 = false; f1 = false; f2 = false;                                   \
        if (c0m | c1m) {                                                      \
            unsigned long long mlo = c0m, mhi = c1m;                          \
            const int n2 = __popcll(c0m) + __popcll(c1m);                     \
            if (n2 <= 3) {                                                    \
                int k0; int k1 = -1; int k2 = -1;                             \
                EXTR(k0) EXTR2(k1) EXTR2(k2)                                  \
                const float* p0 = rcW2 + ((size_t)k0 << 7);                   \
                const float* p1 = rcW2 + ((size_t)(k1 >= 0 ? k1 : k0) << 7);  \
                const float* p2 = rcW2 + ((size_t)(k2 >= 0 ? k2 : k0) << 7);  \
                l0x = p0[lane]; l0y = p0[lane + 64];                          \
                l1x = p1[lane]; l1y = p1[lane + 64];                          \
                l2x = p2[lane]; l2y = p2[lane + 64];                          \
                f0 = true; f1 = (k1 >= 0); f2 = (k2 >= 0);                    \
            } else { /* rare: in-step ascending walk */                       \
                float sx = 0.f, sy = 0.f;                                     \
                while (mlo | mhi) {                                           \
                    int kk; EXTR(kk)                                          \
                    const float* pr = rcW2 + ((size_t)kk << 7);               \
                    sx += pr[lane]; sy += pr[lane + 64];                      \
                }                                                             \
                l0x = sx; l0y = sy;                                           \
                l1x = 0.f; l1y = 0.f; l2x = 0.f; l2y = 0.f;                   \
                f0 = true;                                                    \
            }                                                                 \
        }                                                                     \
    }

    // Main loop: 31 chunks x 8 steps (t=0..247), then tail 248,249.
    // vmcnt: c<=27: issue chunk c+3 then WAITV(8) -- after-issue count past
    // chunk c+1 is exactly chunks c+2 (4) + c+3 (4) = 8, so vmcnt(8)
    // GUARANTEES chunk c+1 retired even with zero gather loads in flight.
    // c==28: issue chunk 31 (1 instr) then drain; c>=29: drain (no-op).
#pragma unroll 1
    for (int c = 0; c < 31; ++c) {
        if (c <= 27)      issue_chunk(hg, ringb, c + 3, 4);
        else if (c == 28) issue_chunk(hg, ringb, 31, 1);
        if (c <= 27) { WAITV(8); } else { WAITV(0); }
        const int t0 = c << 3;
#pragma unroll 1
        for (int g = 0; g < 2; ++g) {
            const int t = t0 + (g << 2);
            STEP(t + 0, 0)
            STEP(t + 1, 1)
            STEP(t + 2, 2)
            STEP(t + 3, 3)
        }
    }
    WAITV(0);
    STEP(248, 0)
    STEP(249, 1)
#undef STEP

    // ---- readout: out[b] = cnt2 @ W3 + T*b3 (ring reused as scratch) ----
    ring[lane]      = cntx;
    ring[lane + 64] = cnty;
    __syncthreads();
    if (lane < DOUT) {
        float o = (float)Tt * b3[lane];
#pragma unroll 8
        for (int k = 0; k < Hh; ++k) o += ring[k] * W3[k * DOUT + lane];
        out[b * DOUT + lane] = o;
    }
}

// ---------------------------------------------------------------------------
extern "C" void kernel_launch(void* const* d_in, const int* in_sizes, int n_in,
                              void* d_out, int out_size, void* d_ws, size_t ws_size,
                              hipStream_t stream) {
    const float* x    = (const float*)d_in[0];
    const float* W1   = (const float*)d_in[1];
    const float* b1   = (const float*)d_in[2];
    const float* rcW1 = (const float*)d_in[3];
    const float* rcb1 = (const float*)d_in[4];
    const float* W2   = (const float*)d_in[5];
    const float* b2   = (const float*)d_in[6];
    const float* rcW2 = (const float*)d_in[7];
    const float* rcb2 = (const float*)d_in[8];
    const float* W3   = (const float*)d_in[9];
    const float* b3   = (const float*)d_in[10];

    float* out = (float*)d_out;
    float* H1  = (float*)d_ws;   // 64000 x 128 f32 = 32.77 MB

    gemm_h1<<<(Bb * Tt) / BM, 256, 0, stream>>>(x, W1, b1, H1);
    recurrent<<<Bb, 64, 0, stream>>>(H1, rcW1, rcb1, W2, b2, rcW2, rcb2, W3,
                                     b3, out);
}